// Round 1
// baseline (246.973 us; speedup 1.0000x reference)
//
#include <hip/hip_runtime.h>

#define BLOCK 256
#define NBLK  512

__device__ __forceinline__ float softplus_f(float x) {
    // stable: softplus(x) = max(x,0) + log1p(exp(-|x|))
    return fmaxf(x, 0.0f) + log1pf(__expf(-fabsf(x)));
}

// Sum over all pairs (a,b) in [0,N)^2 of softplus(v[b]-v[a]) * [ty[a]==1][ty[b]==0].
// Grid-stride over flattened pair index i = a*N + b. With gridDim*blockDim a
// multiple of N (512*256 = 16*8192), each thread's b is constant across
// iterations (v[b],ty[b] loaded once) and a is wave-uniform (ty[a]==0 rows are
// skipped at wave level via execz).
__global__ void pair_sum_kernel(const float* __restrict__ v,
                                const int* __restrict__ ty,
                                double* __restrict__ partials,
                                int N) {
    const long long total  = (long long)N * (long long)N;
    const long long stride = (long long)gridDim.x * blockDim.x;
    const long long i0     = (long long)blockIdx.x * blockDim.x + threadIdx.x;

    float sum = 0.0f;
    if (i0 < total) {
        int a = (int)(i0 / N);
        int b = (int)(i0 % N);
        const int da0 = (int)(stride / N);
        const int db0 = (int)(stride % N);
        const bool bfix = (db0 == 0);

        float vb = v[b];
        int   tb = ty[b];

        for (long long i = i0; i < total; i += stride) {
            if (!bfix) { vb = v[b]; tb = ty[b]; }
            const int ta = ty[a];          // wave-uniform -> scalar branch
            if (ta == 1) {
                const float sp = softplus_f(vb - v[a]);
                if (tb == 0) sum += sp;    // per-lane predication
            }
            a += da0;
            b += db0;
            if (b >= N) { b -= N; ++a; }
        }
    }

    // wave reduce (64 lanes), then cross-wave via LDS
    for (int off = 32; off > 0; off >>= 1)
        sum += __shfl_down(sum, off, 64);

    __shared__ float wsum[BLOCK / 64];
    const int lane = threadIdx.x & 63;
    const int wid  = threadIdx.x >> 6;
    if (lane == 0) wsum[wid] = sum;
    __syncthreads();
    if (threadIdx.x == 0) {
        float t = 0.0f;
        #pragma unroll
        for (int w = 0; w < BLOCK / 64; ++w) t += wsum[w];
        partials[blockIdx.x] = (double)t;   // every block writes (0 if idle)
    }
}

// Single block: sum the per-block partials, count positives/negatives from ty,
// write out = total / (cntPos * cntNeg).
__global__ void finalize_kernel(const double* __restrict__ partials, int nparts,
                                const int* __restrict__ ty, int N,
                                float* __restrict__ out) {
    const int tid = threadIdx.x;

    double s = 0.0;
    for (int k = tid; k < nparts; k += blockDim.x) s += partials[k];

    int cp = 0, cn = 0;
    for (int k = tid; k < N; k += blockDim.x) {
        const int t = ty[k];
        cp += (t == 1);
        cn += (t == 0);
    }

    __shared__ double sd[BLOCK];
    __shared__ int    sp_[BLOCK];
    __shared__ int    sn_[BLOCK];
    sd[tid] = s; sp_[tid] = cp; sn_[tid] = cn;
    __syncthreads();
    for (int off = BLOCK / 2; off > 0; off >>= 1) {
        if (tid < off) {
            sd[tid]  += sd[tid + off];
            sp_[tid] += sp_[tid + off];
            sn_[tid] += sn_[tid + off];
        }
        __syncthreads();
    }
    if (tid == 0) {
        const double denom = (double)sp_[0] * (double)sn_[0];
        out[0] = (float)(sd[0] / denom);
    }
}

extern "C" void kernel_launch(void* const* d_in, const int* in_sizes, int n_in,
                              void* d_out, int out_size, void* d_ws, size_t ws_size,
                              hipStream_t stream) {
    const float* v  = (const float*)d_in[0];   // pred_y, fp32, N = n*K
    const int*   ty = (const int*)d_in[1];     // true_y, int32 in {0,1}
    float* out = (float*)d_out;
    const int N = in_sizes[0];

    double* partials = (double*)d_ws;          // NBLK doubles, fully overwritten

    pair_sum_kernel<<<NBLK, BLOCK, 0, stream>>>(v, ty, partials, N);
    finalize_kernel<<<1, BLOCK, 0, stream>>>(partials, NBLK, ty, N, out);
}

// Round 2
// 74.144 us; speedup vs baseline: 3.3310x; 3.3310x over previous
//
#include <hip/hip_runtime.h>

#define CBLK 256
#define PBLK 256
#define PAIR_BLOCKS 2048

// ---------------------------------------------------------------------------
// Pass 1: compact pred values into dense vpos[] (ty==1) and vneg[] (ty==0)
// arrays using wave-level ballot + one atomic per wave per list. Order is
// arbitrary (sum is order-independent). cnt[0]=|pos|, cnt[1]=|neg| (pre-zeroed
// via hipMemsetAsync — ws is poisoned 0xAA before every launch).
// ---------------------------------------------------------------------------
__global__ void compact_kernel(const float* __restrict__ v,
                               const int* __restrict__ ty,
                               int* __restrict__ cnt,
                               float* __restrict__ vpos,
                               float* __restrict__ vneg,
                               int N) {
    const int i    = blockIdx.x * blockDim.x + threadIdx.x;
    const int lane = threadIdx.x & 63;

    const bool valid = (i < N);
    float val = 0.0f;
    int   t   = -1;
    if (valid) { val = v[i]; t = ty[i]; }

    const bool isP = valid && (t == 1);
    const bool isN = valid && (t == 0);

    const unsigned long long mp = __ballot(isP);
    const unsigned long long mn = __ballot(isN);
    const unsigned long long lt = (lane == 0) ? 0ull : (~0ull >> (64 - lane));

    int basep = 0, basen = 0;
    if (lane == 0) {
        basep = atomicAdd(&cnt[0], __popcll(mp));
        basen = atomicAdd(&cnt[1], __popcll(mn));
    }
    basep = __shfl(basep, 0, 64);
    basen = __shfl(basen, 0, 64);

    if (isP) vpos[basep + __popcll(mp & lt)] = val;
    if (isN) vneg[basen + __popcll(mn & lt)] = val;
}

// ---------------------------------------------------------------------------
// Pass 2: sum softplus(vneg[b] - vpos[a]) over the dense P x Q pair space.
// Thread t owns neg entries b = t, t+256, ... (vn in register); block bid owns
// pos entries a = bid, bid+G, ... (uniform scalar load). No divergence, no
// masking. softplus(x) = max(x,0) + log(1 + exp(-|x|)) with HW v_exp/v_log.
// ---------------------------------------------------------------------------
__global__ void pair_kernel(const int* __restrict__ cnt,
                            const float* __restrict__ vpos,
                            const float* __restrict__ vneg,
                            float* __restrict__ partials) {
    const int P = cnt[0];
    const int Q = cnt[1];

    float acc = 0.0f;
    for (int b = threadIdx.x; b < Q; b += PBLK) {
        const float vn = vneg[b];
        for (int a = blockIdx.x; a < P; a += gridDim.x) {
            const float x = vn - vpos[a];
            const float e = __expf(-fabsf(x));          // v_exp_f32
            acc += fmaxf(x, 0.0f) + __logf(1.0f + e);   // v_log_f32
        }
    }

    // wave reduce, then cross-wave via LDS
    for (int off = 32; off > 0; off >>= 1)
        acc += __shfl_down(acc, off, 64);

    __shared__ float wsum[PBLK / 64];
    const int lane = threadIdx.x & 63;
    const int wid  = threadIdx.x >> 6;
    if (lane == 0) wsum[wid] = acc;
    __syncthreads();
    if (threadIdx.x == 0) {
        float s = 0.0f;
        #pragma unroll
        for (int w = 0; w < PBLK / 64; ++w) s += wsum[w];
        partials[blockIdx.x] = s;   // unconditional: ws is poisoned each launch
    }
}

// ---------------------------------------------------------------------------
// Pass 3: out = sum(partials) / (P * Q), accumulated in double.
// ---------------------------------------------------------------------------
__global__ void finalize_kernel(const float* __restrict__ partials, int nparts,
                                const int* __restrict__ cnt,
                                float* __restrict__ out) {
    const int tid = threadIdx.x;
    double s = 0.0;
    for (int k = tid; k < nparts; k += blockDim.x) s += (double)partials[k];

    __shared__ double sd[256];
    sd[tid] = s;
    __syncthreads();
    for (int off = 128; off > 0; off >>= 1) {
        if (tid < off) sd[tid] += sd[tid + off];
        __syncthreads();
    }
    if (tid == 0) {
        const double denom = (double)cnt[0] * (double)cnt[1];
        out[0] = (float)(sd[0] / denom);
    }
}

extern "C" void kernel_launch(void* const* d_in, const int* in_sizes, int n_in,
                              void* d_out, int out_size, void* d_ws, size_t ws_size,
                              hipStream_t stream) {
    const float* v  = (const float*)d_in[0];   // pred_y fp32, N = n*K
    const int*   ty = (const int*)d_in[1];     // true_y int32 {0,1}
    float* out = (float*)d_out;
    const int N = in_sizes[0];

    // ws layout: [cnt:2 ints][pad][vpos:N f32][vneg:N f32][partials:G f32]
    char*  ws       = (char*)d_ws;
    int*   cnt      = (int*)ws;
    float* vpos     = (float*)(ws + 64);
    float* vneg     = vpos + N;
    float* partials = vneg + N;

    hipMemsetAsync(cnt, 0, 2 * sizeof(int), stream);  // memset node: capturable

    const int cblocks = (N + CBLK - 1) / CBLK;
    compact_kernel<<<cblocks, CBLK, 0, stream>>>(v, ty, cnt, vpos, vneg, N);
    pair_kernel<<<PAIR_BLOCKS, PBLK, 0, stream>>>(cnt, vpos, vneg, partials);
    finalize_kernel<<<1, 256, 0, stream>>>(partials, PAIR_BLOCKS, cnt, out);
}